// Round 1
// baseline (252.593 us; speedup 1.0000x reference)
//
#include <hip/hip_runtime.h>

#define B_DIM 4
#define T_DIM 96
#define N_DIM 512
#define H_DIM 128
#define LDS_STRIDE 136   // 128 + 8 bf16 pad: breaks power-of-2 bank stride, keeps 16B align

typedef __attribute__((ext_vector_type(8))) short short8;
typedef __attribute__((ext_vector_type(4))) float f32x4;

__device__ __forceinline__ unsigned short f2b(float f) {
    union { float f; unsigned u; } c; c.f = f;
    unsigned u = c.u;
    unsigned r = (u + 0x7FFFu + ((u >> 16) & 1u)) >> 16;   // RNE
    return (unsigned short)r;
}
__device__ __forceinline__ float b2f(unsigned short s) {
    union { unsigned u; float f; } c; c.u = ((unsigned)s) << 16;
    return c.f;
}

// One workgroup per (b, n) sequence. Fully fused:
//   GEMM1 (x @ W_exp^T + b_exp) -> prim/gate in LDS (bf16)
//   EMA over T on gate, sigmoid, multiply prim -> pg in LDS (aliases xs)
//   GEMM2 (pg @ W_con^T + b_con) -> out (fp32)
// MFMA 16x16x32 bf16 with W as A-operand, activations as B-operand:
//   D[row=q*4+r][col=lane&15] = row -> output channel (4 consecutive), col -> t.
extern "C" __global__ __launch_bounds__(256, 2)
void mamba_fused(const float* __restrict__ x,
                 const float* __restrict__ W_exp,
                 const float* __restrict__ b_exp,
                 const float* __restrict__ W_con,
                 const float* __restrict__ b_con,
                 float* __restrict__ out)
{
    __shared__ unsigned short xs[T_DIM * LDS_STRIDE];    // x tile bf16; reused as pg
    __shared__ unsigned short prim[T_DIM * LDS_STRIDE];  // primary half, bf16
    __shared__ unsigned short gate[T_DIM * LDS_STRIDE];  // gating half, bf16

    const int tid  = threadIdx.x;
    const int wave = tid >> 6;
    const int lane = tid & 63;
    const int q    = lane >> 4;
    const int l16  = lane & 15;

    const int blk = blockIdx.x;
    const int n   = blk & (N_DIM - 1);
    const int b   = blk >> 9;

    const float* xg = x + ((size_t)b * T_DIM * N_DIM + (size_t)n) * H_DIM;

    // ---- Stage x -> LDS (fp32 -> bf16), coalesced float4 loads ----
    for (int idx = tid; idx < T_DIM * (H_DIM / 4); idx += 256) {
        int t  = idx >> 5;            // H/4 = 32 float4 per row
        int c4 = (idx & 31) << 2;
        float4 v = *(const float4*)(xg + (size_t)t * (N_DIM * H_DIM) + c4);
        ushort4 u;
        u.x = f2b(v.x); u.y = f2b(v.y); u.z = f2b(v.z); u.w = f2b(v.w);
        *(ushort4*)&xs[t * LDS_STRIDE + c4] = u;
    }

    // ---- W_exp fragments (A-operand: A[m=o_local][k]) + biases ----
    short8 wf[4][4];
    float  bias1[4][4];
    {
        const int obase = wave * 64;   // wave covers o in [obase, obase+64)
        for (int ot = 0; ot < 4; ++ot) {
            const float* wrow = W_exp + (size_t)(obase + ot * 16 + l16) * H_DIM + q * 8;
            for (int k0 = 0; k0 < 4; ++k0) {
                float4 v0 = *(const float4*)(wrow + k0 * 32);
                float4 v1 = *(const float4*)(wrow + k0 * 32 + 4);
                short8 f;
                f[0] = (short)f2b(v0.x); f[1] = (short)f2b(v0.y);
                f[2] = (short)f2b(v0.z); f[3] = (short)f2b(v0.w);
                f[4] = (short)f2b(v1.x); f[5] = (short)f2b(v1.y);
                f[6] = (short)f2b(v1.z); f[7] = (short)f2b(v1.w);
                wf[ot][k0] = f;
            }
            for (int r = 0; r < 4; ++r)
                bias1[ot][r] = b_exp[obase + ot * 16 + q * 4 + r];
        }
    }
    __syncthreads();

    // ---- GEMM1: expanded[o][t] tiles, o in [wave*64, wave*64+64) ----
    for (int mt = 0; mt < 6; ++mt) {
        short8 bfr[4];   // B-operand: B[k][n=t_local] = x[t][k]
        const unsigned short* arow = &xs[(mt * 16 + l16) * LDS_STRIDE];
        for (int k0 = 0; k0 < 4; ++k0)
            bfr[k0] = *(const short8*)(arow + k0 * 32 + q * 8);
        const int tcol = mt * 16 + l16;
        for (int ot = 0; ot < 4; ++ot) {
            f32x4 acc = {0.f, 0.f, 0.f, 0.f};
            for (int k0 = 0; k0 < 4; ++k0)
                acc = __builtin_amdgcn_mfma_f32_16x16x32_bf16(wf[ot][k0], bfr[k0], acc, 0, 0, 0);
            const int o = wave * 64 + ot * 16 + q * 4;   // 4 consecutive channels
            ushort4 pk;
            pk.x = f2b(acc[0] + bias1[ot][0]);
            pk.y = f2b(acc[1] + bias1[ot][1]);
            pk.z = f2b(acc[2] + bias1[ot][2]);
            pk.w = f2b(acc[3] + bias1[ot][3]);
            unsigned short* dst = (o < H_DIM) ? prim : gate;   // wave-uniform branch
            *(ushort4*)&dst[tcol * LDS_STRIDE + (o & (H_DIM - 1))] = pk;
        }
    }
    __syncthreads();

    // ---- W_con fragments (issued before EMA so global latency overlaps) ----
    short8 wc[2][4];
    float  bias2[2][4];
    {
        const int obase = wave * 32;
        for (int ot = 0; ot < 2; ++ot) {
            const float* wrow = W_con + (size_t)(obase + ot * 16 + l16) * H_DIM + q * 8;
            for (int k0 = 0; k0 < 4; ++k0) {
                float4 v0 = *(const float4*)(wrow + k0 * 32);
                float4 v1 = *(const float4*)(wrow + k0 * 32 + 4);
                short8 f;
                f[0] = (short)f2b(v0.x); f[1] = (short)f2b(v0.y);
                f[2] = (short)f2b(v0.z); f[3] = (short)f2b(v0.w);
                f[4] = (short)f2b(v1.x); f[5] = (short)f2b(v1.y);
                f[6] = (short)f2b(v1.z); f[7] = (short)f2b(v1.w);
                wc[ot][k0] = f;
            }
            for (int r = 0; r < 4; ++r)
                bias2[ot][r] = b_con[obase + ot * 16 + q * 4 + r];
        }
    }

    // ---- EMA over T + sigmoid + multiply (128 threads, one per feature) ----
    if (tid < H_DIM) {
        const int h = tid;
        float s = 0.f;
        #pragma unroll 4
        for (int t = 0; t < T_DIM; ++t) {
            float g = b2f(gate[t * LDS_STRIDE + h]);
            s = 0.9f * s + 0.1f * g;
            float sig = 1.f / (1.f + __expf(-s));
            float p = b2f(prim[t * LDS_STRIDE + h]);
            xs[t * LDS_STRIDE + h] = f2b(p * sig);   // pg aliases xs
        }
    }
    __syncthreads();

    // ---- GEMM2: out[o][t] tiles, o in [wave*32, wave*32+32) ----
    float* og = out + ((size_t)b * T_DIM * N_DIM + (size_t)n) * H_DIM;
    for (int mt = 0; mt < 6; ++mt) {
        short8 bfr[4];
        const unsigned short* arow = &xs[(mt * 16 + l16) * LDS_STRIDE];
        for (int k0 = 0; k0 < 4; ++k0)
            bfr[k0] = *(const short8*)(arow + k0 * 32 + q * 8);
        const int t = mt * 16 + l16;
        for (int ot = 0; ot < 2; ++ot) {
            f32x4 acc = {0.f, 0.f, 0.f, 0.f};
            for (int k0 = 0; k0 < 4; ++k0)
                acc = __builtin_amdgcn_mfma_f32_16x16x32_bf16(wc[ot][k0], bfr[k0], acc, 0, 0, 0);
            const int o = wave * 32 + ot * 16 + q * 4;
            float4 v;
            v.x = acc[0] + bias2[ot][0];
            v.y = acc[1] + bias2[ot][1];
            v.z = acc[2] + bias2[ot][2];
            v.w = acc[3] + bias2[ot][3];
            *(float4*)(og + (size_t)t * (N_DIM * H_DIM) + o) = v;   // 16B coalesced
        }
    }
}

extern "C" void kernel_launch(void* const* d_in, const int* in_sizes, int n_in,
                              void* d_out, int out_size, void* d_ws, size_t ws_size,
                              hipStream_t stream) {
    const float* x     = (const float*)d_in[0];
    const float* W_exp = (const float*)d_in[1];
    const float* b_exp = (const float*)d_in[2];
    const float* W_con = (const float*)d_in[3];
    const float* b_con = (const float*)d_in[4];
    float* out = (float*)d_out;

    dim3 grid(B_DIM * N_DIM);   // 2048 workgroups, one per (b, n)
    dim3 block(256);
    hipLaunchKernelGGL(mamba_fused, grid, block, 0, stream,
                       x, W_exp, b_exp, W_con, b_con, out);
}

// Round 2
// 230.508 us; speedup vs baseline: 1.0958x; 1.0958x over previous
//
#include <hip/hip_runtime.h>

#define B_DIM 4
#define T_DIM 96
#define N_DIM 512
#define H_DIM 128
#define NH    (N_DIM * H_DIM)

// d_ws layout (in bf16 shorts):
#define WS_WEXP  0        // [256][128] bf16 row-major
#define WS_WCON  32768    // [128][128] bf16 row-major
#define WS_L     49152    // [96][96]  bf16 row-major: L[t][k] = 0.1*0.9^(t-k), k<=t
#define WS_TOTAL 58368

typedef __attribute__((ext_vector_type(8))) short short8;
typedef __attribute__((ext_vector_type(4))) float f32x4;

__device__ __forceinline__ unsigned short f2b_rh(float f) {
    union { float f; unsigned u; } c; c.f = f;
    return (unsigned short)((c.u + 0x8000u) >> 16);   // round-half-up to bf16
}
// pack two fp32 -> bf16x2 (low = a, high = b): 2 adds + 1 v_perm_b32
__device__ __forceinline__ unsigned pack_bf16_2(float a, float b) {
    union { float f; unsigned u; } ca, cb; ca.f = a; cb.f = b;
    return __builtin_amdgcn_perm(cb.u + 0x8000u, ca.u + 0x8000u, 0x07060302u);
}
__device__ __forceinline__ float b2f(unsigned short s) {
    union { unsigned u; float f; } c; c.u = ((unsigned)s) << 16;
    return c.f;
}

// ---- Prep: fp32 weights -> bf16 in ws; build EMA coefficient matrix L ----
extern "C" __global__ void prep_kernel(const float* __restrict__ Wexp,
                                       const float* __restrict__ Wcon,
                                       unsigned short* __restrict__ ws) {
    int i = blockIdx.x * 256 + threadIdx.x;
    if (i < 32768) {
        ws[WS_WEXP + i] = f2b_rh(Wexp[i]);
    } else if (i < 49152) {
        int j = i - 32768;
        ws[WS_WCON + j] = f2b_rh(Wcon[j]);
    } else if (i < WS_TOTAL) {
        int j = i - 49152;
        int t = j / 96, k = j - t * 96;
        float v = 0.0f;
        if (k <= t) v = 0.1f * __expf((float)(t - k) * -0.1053605157f); // 0.1*0.9^(t-k)
        ws[WS_L + j] = f2b_rh(v);
    }
}

// One workgroup per (b, n). Phases:
//   GEMM1 (x from global as B-frags) -> prim [t][h] (b64 writes) + gateT [h][t'] in LDS
//   EMA = L @ G via MFMA (all 4 waves)  -> sigmoid -> * prim -> pg [t][h] (aliases gateT)
//   GEMM2 -> out fp32
// MFMA 16x16x32 bf16 layouts (verified by round-1 pass):
//   A[m=l16][k=q*8+j], B[k=q*8+j][n=l16], D[row=q*4+r][col=l16]
extern "C" __global__ __launch_bounds__(256, 3)
void mamba_fused(const float* __restrict__ x,
                 const unsigned short* __restrict__ ws,
                 const float* __restrict__ b_exp,
                 const float* __restrict__ b_con,
                 float* __restrict__ out)
{
    __shared__ __align__(16) unsigned short prim[T_DIM * 136];  // [t][h], stride 136 (2-way free)
    __shared__ __align__(16) unsigned short gpg[H_DIM * 104];   // gateT [h][t'], stride 104; later pg [t][h], stride 136

    const int tid  = threadIdx.x;
    const int wave = tid >> 6;
    const int lane = tid & 63;
    const int q    = lane >> 4;
    const int l16  = lane & 15;

    const int blk = blockIdx.x;
    const int n   = blk & (N_DIM - 1);
    const int b   = blk >> 9;

    const float* xg = x + ((size_t)b * T_DIM * N_DIM + (size_t)n) * H_DIM;

    // ---- W_exp A-fragments (pre-converted bf16, no VALU conversion) + bias ----
    short8 wf[4][4];
    float4 bias1[4];
    {
        const int obase = wave * 64;
        const unsigned short* wsW = ws + WS_WEXP;
        for (int ot = 0; ot < 4; ++ot) {
            const unsigned short* wrow = wsW + (size_t)(obase + ot * 16 + l16) * H_DIM + q * 8;
            for (int k0 = 0; k0 < 4; ++k0)
                wf[ot][k0] = *(const short8*)(wrow + k0 * 32);
            bias1[ot] = *(const float4*)(b_exp + obase + ot * 16 + q * 4);
        }
    }

    // ---- GEMM1: B-frags of x straight from global (no LDS staging) ----
    for (int mt = 0; mt < 6; ++mt) {
        const float* xrow = xg + (size_t)(mt * 16 + l16) * NH + q * 8;
        short8 bfr[4];
        for (int k0 = 0; k0 < 4; ++k0) {
            float4 v0 = *(const float4*)(xrow + k0 * 32);
            float4 v1 = *(const float4*)(xrow + k0 * 32 + 4);
            union { unsigned u[4]; short8 s; } p;
            p.u[0] = pack_bf16_2(v0.x, v0.y);
            p.u[1] = pack_bf16_2(v0.z, v0.w);
            p.u[2] = pack_bf16_2(v1.x, v1.y);
            p.u[3] = pack_bf16_2(v1.z, v1.w);
            bfr[k0] = p.s;
        }
        const int tcol = mt * 16 + l16;
        for (int ot = 0; ot < 4; ++ot) {
            f32x4 acc = {0.f, 0.f, 0.f, 0.f};
            for (int k0 = 0; k0 < 4; ++k0)
                acc = __builtin_amdgcn_mfma_f32_16x16x32_bf16(wf[ot][k0], bfr[k0], acc, 0, 0, 0);
            const int o = wave * 64 + ot * 16 + q * 4;
            float r0 = acc[0] + bias1[ot].x, r1 = acc[1] + bias1[ot].y;
            float r2 = acc[2] + bias1[ot].z, r3 = acc[3] + bias1[ot].w;
            if (wave < 2) {                       // primary half: [t][h], vectorized
                union { unsigned u[2]; ushort4 s; } pk;
                pk.u[0] = pack_bf16_2(r0, r1);
                pk.u[1] = pack_bf16_2(r2, r3);
                *(ushort4*)&prim[tcol * 136 + o] = pk.s;
            } else {                              // gating half: transposed [h][t']
                const int g = o - 128;
                gpg[(g + 0) * 104 + tcol] = f2b_rh(r0);
                gpg[(g + 1) * 104 + tcol] = f2b_rh(r1);
                gpg[(g + 2) * 104 + tcol] = f2b_rh(r2);
                gpg[(g + 3) * 104 + tcol] = f2b_rh(r3);
            }
        }
    }
    __syncthreads();

    // ---- EMA via MFMA: S^T = G^T (A, M=h) x L^T (B, N=t), K=96 ----
    // Wave w owns h-tiles {2w, 2w+1} x all 6 t-tiles.
    f32x4 eacc[2][6];
    for (int ht = 0; ht < 2; ++ht)
        for (int tt = 0; tt < 6; ++tt)
            eacc[ht][tt] = (f32x4){0.f, 0.f, 0.f, 0.f};
    {
        const unsigned short* wsL = ws + WS_L;
        for (int kf = 0; kf < 3; ++kf) {
            short8 af[2];
            for (int ht = 0; ht < 2; ++ht) {
                const int h = (wave * 2 + ht) * 16 + l16;
                af[ht] = *(const short8*)&gpg[h * 104 + kf * 32 + q * 8];
            }
            for (int tt = 0; tt < 6; ++tt) {
                short8 bf = *(const short8*)(wsL + (size_t)(tt * 16 + l16) * 96 + kf * 32 + q * 8);
                eacc[0][tt] = __builtin_amdgcn_mfma_f32_16x16x32_bf16(af[0], bf, eacc[0][tt], 0, 0, 0);
                eacc[1][tt] = __builtin_amdgcn_mfma_f32_16x16x32_bf16(af[1], bf, eacc[1][tt], 0, 0, 0);
            }
        }
    }

    // ---- W_con fragments + bias (load before barrier to hide latency) ----
    short8 wc[2][4];
    float4 bias2[2];
    {
        const int obase = wave * 32;
        const unsigned short* wsW = ws + WS_WCON;
        for (int ot = 0; ot < 2; ++ot) {
            const unsigned short* wrow = wsW + (size_t)(obase + ot * 16 + l16) * H_DIM + q * 8;
            for (int k0 = 0; k0 < 4; ++k0)
                wc[ot][k0] = *(const short8*)(wrow + k0 * 32);
            bias2[ot] = *(const float4*)(b_con + obase + ot * 16 + q * 4);
        }
    }
    __syncthreads();   // all gateT reads complete before pg overwrites gpg

    // ---- sigmoid(EMA) * prim -> pg [t][h] stride 136 (aliases gpg) ----
    for (int ht = 0; ht < 2; ++ht) {
        const int hb = (wave * 2 + ht) * 16 + q * 4;
        for (int tt = 0; tt < 6; ++tt) {
            const int t = tt * 16 + l16;
            ushort4 pv = *(const ushort4*)&prim[t * 136 + hb];
            f32x4 s = eacc[ht][tt];
            float sg0 = __fdividef(1.f, 1.f + __expf(-s[0]));
            float sg1 = __fdividef(1.f, 1.f + __expf(-s[1]));
            float sg2 = __fdividef(1.f, 1.f + __expf(-s[2]));
            float sg3 = __fdividef(1.f, 1.f + __expf(-s[3]));
            float p0 = b2f(pv.x) * sg0, p1 = b2f(pv.y) * sg1;
            float p2 = b2f(pv.z) * sg2, p3 = b2f(pv.w) * sg3;
            union { unsigned u[2]; ushort4 s; } pk;
            pk.u[0] = pack_bf16_2(p0, p1);
            pk.u[1] = pack_bf16_2(p2, p3);
            *(ushort4*)&gpg[t * 136 + hb] = pk.s;
        }
    }
    __syncthreads();

    // ---- GEMM2: out[o][t] = Wc @ pg^T + b ----
    float* og = out + ((size_t)b * T_DIM * N_DIM + (size_t)n) * H_DIM;
    for (int mt = 0; mt < 6; ++mt) {
        short8 bfr[4];
        const unsigned short* prow = &gpg[(mt * 16 + l16) * 136];
        for (int k0 = 0; k0 < 4; ++k0)
            bfr[k0] = *(const short8*)(prow + k0 * 32 + q * 8);
        const int t = mt * 16 + l16;
        for (int ot = 0; ot < 2; ++ot) {
            f32x4 acc = {0.f, 0.f, 0.f, 0.f};
            for (int k0 = 0; k0 < 4; ++k0)
                acc = __builtin_amdgcn_mfma_f32_16x16x32_bf16(wc[ot][k0], bfr[k0], acc, 0, 0, 0);
            const int o = wave * 32 + ot * 16 + q * 4;
            float4 v;
            v.x = acc[0] + bias2[ot].x;
            v.y = acc[1] + bias2[ot].y;
            v.z = acc[2] + bias2[ot].z;
            v.w = acc[3] + bias2[ot].w;
            *(float4*)(og + (size_t)t * NH + o) = v;
        }
    }
}

extern "C" void kernel_launch(void* const* d_in, const int* in_sizes, int n_in,
                              void* d_out, int out_size, void* d_ws, size_t ws_size,
                              hipStream_t stream) {
    const float* x     = (const float*)d_in[0];
    const float* W_exp = (const float*)d_in[1];
    const float* b_exp = (const float*)d_in[2];
    const float* W_con = (const float*)d_in[3];
    const float* b_con = (const float*)d_in[4];
    float* out = (float*)d_out;
    unsigned short* ws = (unsigned short*)d_ws;

    hipLaunchKernelGGL(prep_kernel, dim3(WS_TOTAL / 256), dim3(256), 0, stream,
                       W_exp, W_con, ws);
    hipLaunchKernelGGL(mamba_fused, dim3(B_DIM * N_DIM), dim3(256), 0, stream,
                       x, ws, b_exp, b_con, out);
}